// Round 4
// baseline (29.329 us; speedup 1.0000x reference)
//
#include <hip/hip_runtime.h>

#define H 128
#define N 1024
#define SLOTS 144   // >= max TOT8 (136) + 8 prefetch slack

// ---------------------------------------------------------------------------
// prep: grid N/4 = 256 blocks x 512 threads.
//   Computes a sign-partition permutation of h (positives of W2 first,
//   each group zero-padded to a multiple of 8), then
//     e = x/||x||
//     LpS[slot(h)][i] = w2[h]*(e_i.W1L[:,h] + b1[h])   (slot-major, i minor)
//     Rt [slot(h)][j] = w2[h]*(e_j.W1R[:,h])
//     c[j] = sum_h Rt-value (pre-permutation sum, softmax-relevant j part)
//     meta = {P8, TOT8}
//   Identity: sum_h w2*relu(L+b1+R) = 0.5*(rowconst + c_j + sum_pos|u| - sum_neg|u|)
//   with u = w2*(L+b1+R); rowconst cancels under softmax.
// ---------------------------------------------------------------------------
__global__ __launch_bounds__(512) void prep_kernel(
    const float* __restrict__ x, const float* __restrict__ W1,
    const float* __restrict__ b1, const float* __restrict__ W2,
    float* __restrict__ LpS, float* __restrict__ Rt,
    float* __restrict__ c, int* __restrict__ meta)
{
    constexpr int PF = 8;
    __shared__ float e_s[4][H];
    __shared__ float cred[4][2];
    __shared__ int   slot_s[H];
    __shared__ int   cnt_s[2];
    __shared__ int   meta_s[3];     // P8, TOT8, P
    const int t = threadIdx.x;
    const int i0 = blockIdx.x * 4;

    // ---- sign ballots (waves 0,1 cover h = t) ----
    bool pos = false; int rank = 0;
    if (t < H) {
        const int lane = t & 63;
        pos = (W2[t] >= 0.f);
        const unsigned long long bal = __ballot(pos);
        rank = __popcll(bal & ((1ull << lane) - 1ull));
        if (lane == 0) cnt_s[t >> 6] = __popcll(bal);
    }
    // ---- normalize rows (waves 0-3, wave w owns row w) ----
    if (t < 256) {
        const int row = t >> 6, lane = t & 63;
        const float2 v = *reinterpret_cast<const float2*>(&x[(i0 + row) * H + 2 * lane]);
        float s = v.x * v.x + v.y * v.y;
#pragma unroll
        for (int off = 32; off; off >>= 1) s += __shfl_xor(s, off);
        const float rn = 1.0f / fmaxf(sqrtf(s), 1e-12f);
        e_s[row][2 * lane]     = v.x * rn;
        e_s[row][2 * lane + 1] = v.y * rn;
    }
    __syncthreads();

    // ---- permutation slots ----
    if (t < H) {
        const int c0 = cnt_s[0];
        const int P  = c0 + cnt_s[1];
        const int P8 = (P + 7) & ~7;
        const int lane = t & 63;
        int slot;
        if (pos) slot = (t < 64 ? 0 : c0) + rank;
        else     slot = P8 + (t < 64 ? 0 : 64 - c0) + (lane - rank);
        slot_s[t] = slot;
        if (t == 0) {
            meta_s[0] = P8;
            meta_s[1] = P8 + ((H - P + 7) & ~7);  // TOT8
            meta_s[2] = P;
        }
    }
    __syncthreads();

    // ---- dual GEMM, PF-pipelined W1 loads ----
    const int h = t & (H - 1);
    const int q = t >> 7;                // 0,1 -> L ; 2,3 -> R
    const int r0 = (q & 1) * 2;          // row pair {0,1} or {2,3}
    const float* Wb = W1 + (q >= 2 ? H * H : 0) + h;

    float acc0 = 0.f, acc1 = 0.f;
    float wbuf[PF];
#pragma unroll
    for (int p = 0; p < PF; ++p) wbuf[p] = Wb[p * H];

    for (int kb = 0; kb < H - PF; kb += PF) {
#pragma unroll
        for (int p = 0; p < PF; ++p) {
            const float w = wbuf[p];
            wbuf[p] = Wb[(kb + p + PF) * H];
            acc0 = fmaf(e_s[r0][kb + p],     w, acc0);
            acc1 = fmaf(e_s[r0 + 1][kb + p], w, acc1);
        }
    }
#pragma unroll
    for (int p = 0; p < PF; ++p) {
        const int k = H - PF + p;
        acc0 = fmaf(e_s[r0][k],     wbuf[p], acc0);
        acc1 = fmaf(e_s[r0 + 1][k], wbuf[p], acc1);
    }

    const float w2h = W2[h];
    const int slot = slot_s[h];
    if (q < 2) {
        const float bb = b1[h];
        LpS[slot * N + (i0 + r0)]     = w2h * (acc0 + bb);
        LpS[slot * N + (i0 + r0 + 1)] = w2h * (acc1 + bb);
    } else {
        const float v0 = w2h * acc0, v1 = w2h * acc1;
        Rt[slot * N + (i0 + r0)]     = v0;
        Rt[slot * N + (i0 + r0 + 1)] = v1;
        float s0 = v0, s1 = v1;          // c_j partials over h
#pragma unroll
        for (int off = 32; off; off >>= 1) {
            s0 += __shfl_xor(s0, off);
            s1 += __shfl_xor(s1, off);
        }
        const int wv = t >> 6;           // 4..7
        if ((t & 63) == 0) { cred[wv - 4][0] = s0; cred[wv - 4][1] = s1; }
    }
    __syncthreads();

    if (t < 4)
        c[i0 + t] = cred[(t >> 1) * 2][t & 1] + cred[(t >> 1) * 2 + 1][t & 1];

    // ---- zero the pad slots (this block's 4 columns) ----
    {
        const int P8m = meta_s[0], T8m = meta_s[1], Pm = meta_s[2];
        const float4 z = {0.f, 0.f, 0.f, 0.f};
        if (t >= 64 && t < 72) {                 // pads after positives
            const int k = t - 64;
            if (k < P8m - Pm) {
                const int ps = Pm + k;
                *reinterpret_cast<float4*>(&LpS[ps * N + i0]) = z;
                *reinterpret_cast<float4*>(&Rt[ps * N + i0])  = z;
            }
        } else if (t >= 72 && t < 80) {          // pads after negatives
            const int k = t - 72;
            const int base2 = P8m + (H - Pm);
            if (k < T8m - base2) {
                const int ps = base2 + k;
                *reinterpret_cast<float4*>(&LpS[ps * N + i0]) = z;
                *reinterpret_cast<float4*>(&Rt[ps * N + i0])  = z;
            }
        }
    }
    if (blockIdx.x == 0 && t == 0) { meta[0] = meta_s[0]; meta[1] = meta_s[1]; }
}

// ---------------------------------------------------------------------------
// adj: grid N/4 = 256 blocks x 512 threads; thread = 4 rows x 2 cols.
//   A[i][j] = sum_{slot<P8} |lv+r| - sum_{P8<=slot<TOT8} |lv+r|
//   logit' = 0.5*(c_j + A); softmax over j block-locally.
//   Inner loop: 2 VALU/el (add + add/sub with abs modifier), 1 LDS b128
//   broadcast per slot, PF=8 rotating float2 R prefetch (flows across the
//   sign boundary since groups are 8-aligned and contiguous).
// ---------------------------------------------------------------------------
__global__ __launch_bounds__(512) void adj_kernel(
    const float* __restrict__ LpS, const float* __restrict__ Rt,
    const float* __restrict__ c, const int* __restrict__ meta,
    float* __restrict__ out)
{
    constexpr int II = 4;
    __shared__ float4 LsT[SLOTS];
    __shared__ float red_m[II][8];
    __shared__ float red_s[II][8];

    const int t = threadIdx.x;
    const int lane = t & 63, wave = t >> 6;
    const int i0 = blockIdx.x * II;
    const int j0 = t * 2;

    const int P8 = meta[0], T8 = meta[1];

    if (t < T8)
        LsT[t] = *reinterpret_cast<const float4*>(&LpS[t * N + i0]);
    const float2 cj = *reinterpret_cast<const float2*>(&c[j0]);
    __syncthreads();

    float accx[II], accy[II];
#pragma unroll
    for (int ii = 0; ii < II; ++ii) { accx[ii] = cj.x; accy[ii] = cj.y; }

    const float* Rp = Rt + j0;
    float2 rbuf[8];
#pragma unroll
    for (int p = 0; p < 8; ++p)
        rbuf[p] = *reinterpret_cast<const float2*>(&Rp[p * N]);

    int hb = 0;
    for (; hb < P8; hb += 8) {           // positive group: acc += |u|
#pragma unroll
        for (int p = 0; p < 8; ++p) {
            const int s = hb + p;
            const float2 r = rbuf[p];
            rbuf[p] = *reinterpret_cast<const float2*>(&Rp[(s + 8) * N]);
            const float4 lv = LsT[s];
            const float* lp = &lv.x;
#pragma unroll
            for (int ii = 0; ii < II; ++ii) {
                accx[ii] += fabsf(lp[ii] + r.x);
                accy[ii] += fabsf(lp[ii] + r.y);
            }
        }
    }
    for (; hb < T8; hb += 8) {           // negative group: acc -= |u|
#pragma unroll
        for (int p = 0; p < 8; ++p) {
            const int s = hb + p;
            const float2 r = rbuf[p];
            rbuf[p] = *reinterpret_cast<const float2*>(&Rp[(s + 8) * N]);
            const float4 lv = LsT[s];
            const float* lp = &lv.x;
#pragma unroll
            for (int ii = 0; ii < II; ++ii) {
                accx[ii] -= fabsf(lp[ii] + r.x);
                accy[ii] -= fabsf(lp[ii] + r.y);
            }
        }
    }

#pragma unroll
    for (int ii = 0; ii < II; ++ii) { accx[ii] *= 0.5f; accy[ii] *= 0.5f; }

    // ---- softmax over j (block = full row) ----
#pragma unroll
    for (int ii = 0; ii < II; ++ii) {
        float m = fmaxf(accx[ii], accy[ii]);
#pragma unroll
        for (int off = 32; off; off >>= 1) m = fmaxf(m, __shfl_xor(m, off));
        if (lane == 0) red_m[ii][wave] = m;
    }
    __syncthreads();

    float mm[II];
#pragma unroll
    for (int ii = 0; ii < II; ++ii) {
        float m = red_m[ii][0];
#pragma unroll
        for (int w = 1; w < 8; ++w) m = fmaxf(m, red_m[ii][w]);
        mm[ii] = m;
    }

#pragma unroll
    for (int ii = 0; ii < II; ++ii) {
        accx[ii] = expf(accx[ii] - mm[ii]);
        accy[ii] = expf(accy[ii] - mm[ii]);
        float s = accx[ii] + accy[ii];
#pragma unroll
        for (int off = 32; off; off >>= 1) s += __shfl_xor(s, off);
        if (lane == 0) red_s[ii][wave] = s;
    }
    __syncthreads();

#pragma unroll
    for (int ii = 0; ii < II; ++ii) {
        float s = red_s[ii][0];
#pragma unroll
        for (int w = 1; w < 8; ++w) s += red_s[ii][w];
        const float r = 1.0f / s;
        float2 o;
        o.x = accx[ii] * r;
        o.y = accy[ii] * r;
        *reinterpret_cast<float2*>(&out[(i0 + ii) * N + j0]) = o;
    }
}

extern "C" void kernel_launch(void* const* d_in, const int* in_sizes, int n_in,
                              void* d_out, int out_size, void* d_ws, size_t ws_size,
                              hipStream_t stream) {
    const float* x  = (const float*)d_in[0];   // (N,H)
    const float* W1 = (const float*)d_in[1];   // (2H,H)
    const float* b1 = (const float*)d_in[2];   // (H,)
    const float* W2 = (const float*)d_in[3];   // (H,1)
    // d_in[4] = b2 — cancels under softmax, not needed.
    float* out = (float*)d_out;

    float* wsf = (float*)d_ws;
    float* LpS = wsf;                    // SLOTS*N
    float* Rt  = LpS + SLOTS * N;        // SLOTS*N
    float* cc  = Rt + SLOTS * N;         // N
    int*   meta = (int*)(cc + N);        // 2 ints

    prep_kernel<<<N / 4, 512, 0, stream>>>(x, W1, b1, W2, LpS, Rt, cc, meta);
    adj_kernel<<<N / 4, 512, 0, stream>>>(LpS, Rt, cc, meta, out);
}